// Round 1
// baseline (264.292 us; speedup 1.0000x reference)
//
#include <hip/hip_runtime.h>
#include <math.h>

#define NN 100000
#define D_IN 128
#define D_H1 128
#define D_H2 64
#define D_O 10
#define NB 256          // node buckets for counting-sort CSR build
#define BDIV 391        // bucket(d) = d / 391  (255*391 = 99705 <= d < 100000 -> 255)
#define ECH 4096        // edges per chunk (histo/scatter)
#define COLCAP 8192     // LDS col capacity per bucket (mean 6250, sigma 79 -> +24s)

// ---- workspace layout (bytes) ----
static const size_t OFF_G1     = 0;                 // N*128 bf16 = 25.6 MB
static const size_t OFF_G2     = 25600000;          // N*64 bf16 = 12.8 MB (g1 live during fused gather)
static const size_t OFF_W1T    = 40000000;          // 128*128 bf16 = 32 KB (pre-packed W1^T)
static const size_t OFF_W2T    = 40100000;          // 64*128 bf16 = 16 KB (pre-packed W2^T)
static const size_t OFF_PART   = 76800000;          // E uint32 = 6.4 MB (packed d_local|src)
static const size_t OFF_COL    = 102400000;         // E int32 = 6.4 MB
static const size_t OFF_DIS    = 108800000;         // N f32
static const size_t OFF_ROWPTR = 109300000;         // (N+1) int32
static const size_t OFF_HIST   = 109800000;         // NB * nchunk int32 (~400 KB)
static const size_t OFF_TOT    = 110700000;         // NB int32

typedef __attribute__((ext_vector_type(8))) short short8;
typedef __attribute__((ext_vector_type(4))) float floatx4;

// ---- bf16 helpers (RNE; values are finite) ----
__device__ inline unsigned int pack_bf2(float a, float b) {
  unsigned int ua = __float_as_uint(a);
  ua += 0x7fffu + ((ua >> 16) & 1u);
  unsigned int ub = __float_as_uint(b);
  ub += 0x7fffu + ((ub >> 16) & 1u);
  return (ua >> 16) | (ub & 0xffff0000u);
}
__device__ inline unsigned short bf16u(float a) {
  unsigned int ua = __float_as_uint(a);
  ua += 0x7fffu + ((ua >> 16) & 1u);
  return (unsigned short)(ua >> 16);
}
__device__ inline float bflo(unsigned int u) { return __uint_as_float(u << 16); }
__device__ inline float bfhi(unsigned int u) { return __uint_as_float(u & 0xffff0000u); }
__device__ inline short8 as_short8(uint4 u) {
  union { uint4 u4; short8 s8; } c; c.u4 = u; return c.s8;
}
__device__ inline void acc_u4(float* acc, uint4 u) {
  acc[0] += bflo(u.x); acc[1] += bfhi(u.x);
  acc[2] += bflo(u.y); acc[3] += bfhi(u.y);
  acc[4] += bflo(u.z); acc[5] += bfhi(u.z);
  acc[6] += bflo(u.w); acc[7] += bfhi(u.w);
}

// ---- 1. per-chunk bucket histogram: H[b][c] (LDS atomics only) ----
// Also folds the one-time weight transpose+bf16 pack into the first 96 blocks
// (w1t: 64 blocks x 256, w2t: 32 blocks x 256) -- zero extra launches; w1t/w2t
// are only consumed 4 dispatches later (gemm / gather1).
__global__ __launch_bounds__(256) void histo_kernel(
    const int* __restrict__ dst, int* __restrict__ H, int E, int nchunk,
    const float* __restrict__ W1, const float* __restrict__ W2,
    unsigned short* __restrict__ w1t, unsigned short* __restrict__ w2t) {
  __shared__ int hist[NB];
  const int tid = threadIdx.x;
  hist[tid] = 0;
  __syncthreads();
  const int e0 = blockIdx.x * ECH;
#pragma unroll
  for (int i = 0; i < ECH / 256; ++i) {
    int e = e0 + i * 256 + tid;
    if (e < E) atomicAdd(&hist[dst[e] / BDIV], 1);
  }
  __syncthreads();
  H[tid * nchunk + blockIdx.x] = hist[tid];
  // one-time weight pack (nchunk = 391 >= 96 for this problem size)
  if (blockIdx.x < 64) {            // W1^T: [128][128] bf16
    int o = blockIdx.x * 256 + tid;
    int nn = o >> 7, k = o & 127;
    w1t[o] = bf16u(W1[(size_t)k * D_H1 + nn]);
  } else if (blockIdx.x < 96) {     // W2^T: [64][128] bf16
    int o = (blockIdx.x - 64) * 256 + tid;
    int nn = o >> 7, k = o & 127;
    w2t[o] = bf16u(W2[(size_t)k * D_H2 + nn]);
  }
}

// ---- 2. per-bucket exclusive scan over chunks (in place) + bucket totals ----
__global__ __launch_bounds__(256) void bucket_scan_kernel(
    int* __restrict__ H, int* __restrict__ total, int nchunk) {
  __shared__ int sm[256];
  const int tid = threadIdx.x;
  int* row = H + (size_t)blockIdx.x * nchunk;
  int carry = 0;
  for (int t0 = 0; t0 < nchunk; t0 += 256) {
    int idx = t0 + tid;
    int v = (idx < nchunk) ? row[idx] : 0;
    sm[tid] = v;
    __syncthreads();
#pragma unroll
    for (int off = 1; off < 256; off <<= 1) {
      int t2 = (tid >= off) ? sm[tid - off] : 0;
      __syncthreads();
      sm[tid] += t2;
      __syncthreads();
    }
    int incl = sm[tid];
    int ttot = sm[255];
    __syncthreads();  // all reads done before next-tile overwrite
    if (idx < nchunk) row[idx] = carry + incl - v;
    carry += ttot;
  }
  if (tid == 0) total[blockIdx.x] = carry;
}

// ---- 3. deterministic scatter into bucket segments (LDS rank, NO global atomics).
// Bucket bases computed by inline LDS scan of totals (base_scan dispatch removed).
// part entry packed: (d_local << 17) | src  (src < 2^17, d_local < 391 < 2^9).
__global__ __launch_bounds__(256) void scatter_kernel(
    const int* __restrict__ src, const int* __restrict__ dst,
    const int* __restrict__ H, const int* __restrict__ total,
    unsigned int* __restrict__ part, int E, int nchunk) {
  __shared__ int sm[NB];
  __shared__ int offs_s[NB];
  __shared__ int base_s[NB];
  __shared__ int cnt[NB];
  const int tid = threadIdx.x;
  // inline exclusive scan of totals -> base_s
  {
    int v = total[tid];
    sm[tid] = v;
    __syncthreads();
#pragma unroll
    for (int off = 1; off < 256; off <<= 1) {
      int t2 = (tid >= off) ? sm[tid - off] : 0;
      __syncthreads();
      sm[tid] += t2;
      __syncthreads();
    }
    base_s[tid] = sm[tid] - v;
  }
  offs_s[tid] = H[tid * nchunk + blockIdx.x];
  cnt[tid] = 0;
  __syncthreads();
  const int e0 = blockIdx.x * ECH;
#pragma unroll
  for (int i = 0; i < ECH / 256; ++i) {
    int e = e0 + i * 256 + tid;
    if (e < E) {
      int d = dst[e];
      int s = src[e];
      int b = d / BDIV;
      int r = atomicAdd(&cnt[b], 1);  // LDS only
      unsigned int p = ((unsigned int)(d - b * BDIV) << 17) | (unsigned int)s;
      part[(size_t)base_s[b] + offs_s[b] + r] = p;
    }
  }
}

// ---- 4. per-bucket CSR finalize: deg->dis, row_ptr, col (all coalesced writes,
// col staged in LDS; one block per bucket). NO global atomics. ebase/ecnt from
// inline totals scan.
__global__ __launch_bounds__(256) void bucket_csr_kernel(
    const unsigned int* __restrict__ part, const int* __restrict__ total,
    int* __restrict__ row_ptr, float* __restrict__ dis,
    int* __restrict__ col, int n, int E) {
  __shared__ int sm[256];
  __shared__ int ldeg[BDIV + 1];
  __shared__ int lofs[BDIV + 1];
  __shared__ int col_s[COLCAP];
  __shared__ int ebase_s, ecnt_s;
  const int tid = threadIdx.x;
  const int b = blockIdx.x;
  const int lo = b * BDIV;
  const int nn = min(n - lo, BDIV);
  // inline scan of totals for this bucket's base
  {
    int v = total[tid];
    sm[tid] = v;
    __syncthreads();
#pragma unroll
    for (int off = 1; off < 256; off <<= 1) {
      int t2 = (tid >= off) ? sm[tid - off] : 0;
      __syncthreads();
      sm[tid] += t2;
      __syncthreads();
    }
    if (tid == b) { ebase_s = sm[tid] - v; ecnt_s = v; }
  }
  for (int t = tid; t <= BDIV; t += 256) ldeg[t] = 0;
  __syncthreads();
  const int ebase = ebase_s;
  const int ecnt = ecnt_s;
  // P1: degree count (LDS atomics)
  for (int i0 = 0; i0 < ecnt; i0 += 256) {
    int idx = i0 + tid;
    if (idx < ecnt) atomicAdd(&ldeg[part[ebase + idx] >> 17], 1);
  }
  __syncthreads();
  // P2: exclusive scan of ldeg -> lofs
  int carry = 0;
  for (int t0 = 0; t0 < BDIV + 1; t0 += 256) {
    int idx = t0 + tid;
    int v = (idx <= BDIV) ? ldeg[idx] : 0;
    sm[tid] = v;
    __syncthreads();
#pragma unroll
    for (int off = 1; off < 256; off <<= 1) {
      int t2 = (tid >= off) ? sm[tid - off] : 0;
      __syncthreads();
      sm[tid] += t2;
      __syncthreads();
    }
    int incl = sm[tid];
    int ttot = sm[255];
    __syncthreads();
    if (idx <= BDIV) lofs[idx] = carry + incl - v;
    carry += ttot;
  }
  __syncthreads();
  for (int t = tid; t < nn; t += 256) {
    row_ptr[lo + t] = ebase + lofs[t];
    dis[lo + t] = rsqrtf((float)ldeg[t] + 1.0f);
  }
  if (b == NB - 1 && tid == 0) row_ptr[n] = E;
  __syncthreads();
  // P3: bin srcs into LDS col (lofs doubles as cursor)
  for (int i0 = 0; i0 < ecnt; i0 += 256) {
    int idx = i0 + tid;
    if (idx < ecnt) {
      unsigned int p = part[ebase + idx];
      int r = atomicAdd(&lofs[p >> 17], 1);
      if (r < COLCAP) col_s[r] = (int)(p & 0x1FFFFu);
    }
  }
  __syncthreads();
  // P4: coalesced col writeback
  const int m = min(ecnt, COLCAP);
  for (int idx = tid; idx < m; idx += 256) col[ebase + idx] = col_s[idx];
}

// ---- MFMA GEMM (layer 1): out = bf16(dis * (A_f32 @ W)), K=128.
// B-operand read directly from pre-packed global W^T bf16 (L1/L2-resident 32 KB)
// -> no per-block LDS weight staging; LDS = 17.4 KB (was 52 KB) for occupancy.
template <int NOUT>
__global__ __launch_bounds__(256) void gemm_mfma_kernel(
    const float* __restrict__ A_, const unsigned short* __restrict__ wt,
    const float* __restrict__ dis, unsigned short* __restrict__ out, int nrows) {
  constexpr int K = 128;
  constexpr int NT = NOUT / 16;
  constexpr int LDW = K + 8;  // 272B row stride: 16B-aligned, b128 conflict-free
  __shared__ unsigned short buf[4 * 16 * LDW];
  const int tid = threadIdx.x;

  const int wave = tid >> 6;
  const int lane = tid & 63;
  const int quad = lane >> 4;
  const int cg = lane & 15;
  const int row0w = blockIdx.x * 64 + wave * 16;

  short8 afr[4];
  {
    int row = row0w + cg;
    if (row > nrows - 1) row = nrows - 1;  // clamp: garbage rows never stored
#pragma unroll
    for (int kb = 0; kb < 4; ++kb) {
      const float* p = A_ + (size_t)row * K + kb * 32 + quad * 8;
      float4 v0 = *(const float4*)(p);
      float4 v1 = *(const float4*)(p + 4);
      uint4 u;
      u.x = pack_bf2(v0.x, v0.y); u.y = pack_bf2(v0.z, v0.w);
      u.z = pack_bf2(v1.x, v1.y); u.w = pack_bf2(v1.z, v1.w);
      afr[kb] = as_short8(u);
    }
  }

  floatx4 acc[NT];
#pragma unroll
  for (int t = 0; t < NT; ++t) acc[t] = (floatx4){0.f, 0.f, 0.f, 0.f};
#pragma unroll
  for (int t = 0; t < NT; ++t) {
    const unsigned short* wrow = wt + (size_t)(t * 16 + cg) * K;
#pragma unroll
    for (int kb = 0; kb < 4; ++kb) {
      short8 bfr = *(const short8*)(wrow + kb * 32 + quad * 8);
      acc[t] = __builtin_amdgcn_mfma_f32_16x16x32_bf16(afr[kb], bfr, acc[t], 0, 0, 0);
    }
  }

  float4 dv4 = *(const float4*)(dis + row0w + quad * 4);  // OOB-safe: ws slack
  float dvs[4] = {dv4.x, dv4.y, dv4.z, dv4.w};
  unsigned short* mybuf = buf + wave * 16 * LDW;
#pragma unroll
  for (int t = 0; t < NT; ++t)
#pragma unroll
    for (int r = 0; r < 4; ++r)
      mybuf[(quad * 4 + r) * LDW + t * 16 + cg] = bf16u(acc[t][r] * dvs[r]);
  __syncthreads();

  constexpr int CHUNKS = NOUT / 8;
  constexpr int RPI = 64 / CHUNKS;
  int cid = lane % CHUNKS;
  int rs = lane / CHUNKS;
#pragma unroll
  for (int i = 0; i < 16 / RPI; ++i) {
    int r = rs + i * RPI;
    int grow = row0w + r;
    if (grow < nrows) {
      uint4 u = *(const uint4*)(mybuf + r * LDW + cid * 8);
      *(uint4*)(out + (size_t)grow * NOUT + cid * 8) = u;
    }
  }
}

// ---- Fused layer-1 gather + ReLU + gemm2 (h1 @ W2, MFMA) -> g2.
// Block = 16 nodes; grid = NN/16 exactly.
// W2^T read directly from pre-packed global bf16 (16 KB, L1-resident) -> LDS
// down to 6.9 KB; __launch_bounds__(256,8) forces 8 waves/SIMD (VGPR<=64) so
// the random-gather latency is covered by full occupancy (was 57%).
__global__ __launch_bounds__(256, 8) void gather1_gemm2_kernel(
    const unsigned short* __restrict__ g, const int* __restrict__ col,
    const int* __restrict__ row_ptr, const float* __restrict__ dis,
    const float* __restrict__ b1, const unsigned short* __restrict__ w2t,
    unsigned short* __restrict__ g2, int n) {
  constexpr int K = D_H1;        // 128
  constexpr int LDW = K + 8;     // 136
  constexpr int LDO = 80;        // 160B row stride: 16B-aligned
  __shared__ unsigned short hl[16 * LDW];     // h tile bf16, 4.4 KB
  __shared__ unsigned short obuf[16 * LDO];   // out tile, 2.56 KB
  const int tid = threadIdx.x;
  const int row0 = blockIdx.x * 16;

  // ---- gather phase: 16 nodes x 16 lanes x 8 feats ----
  {
    const int v = row0 + (tid >> 4);
    const int c = (tid & 15) * 8;
    const int start = row_ptr[v];
    const int end = row_ptr[v + 1];
    float acc[8];
#pragma unroll
    for (int q = 0; q < 8; ++q) acc[q] = 0.f;
    acc_u4(acc, *(const uint4*)(g + (size_t)v * K + c));  // self-loop
    int e = start;
    for (; e + 4 <= end; e += 4) {
      int s0 = col[e + 0], s1 = col[e + 1], s2 = col[e + 2], s3 = col[e + 3];
      uint4 u0 = *(const uint4*)(g + (size_t)s0 * K + c);
      uint4 u1 = *(const uint4*)(g + (size_t)s1 * K + c);
      uint4 u2 = *(const uint4*)(g + (size_t)s2 * K + c);
      uint4 u3 = *(const uint4*)(g + (size_t)s3 * K + c);
      acc_u4(acc, u0); acc_u4(acc, u1); acc_u4(acc, u2); acc_u4(acc, u3);
    }
    for (; e < end; ++e) {
      uint4 u = *(const uint4*)(g + (size_t)col[e] * K + c);
      acc_u4(acc, u);
    }
    float dv = dis[v];
    float4 bv0 = *(const float4*)(b1 + c);
    float4 bv1 = *(const float4*)(b1 + c + 4);
    float r0 = fmaxf(dv * acc[0] + bv0.x, 0.f);
    float r1 = fmaxf(dv * acc[1] + bv0.y, 0.f);
    float r2 = fmaxf(dv * acc[2] + bv0.z, 0.f);
    float r3 = fmaxf(dv * acc[3] + bv0.w, 0.f);
    float r4 = fmaxf(dv * acc[4] + bv1.x, 0.f);
    float r5 = fmaxf(dv * acc[5] + bv1.y, 0.f);
    float r6 = fmaxf(dv * acc[6] + bv1.z, 0.f);
    float r7 = fmaxf(dv * acc[7] + bv1.w, 0.f);
    uint4 o;
    o.x = pack_bf2(r0, r1);
    o.y = pack_bf2(r2, r3);
    o.z = pack_bf2(r4, r5);
    o.w = pack_bf2(r6, r7);
    *(uint4*)(hl + (tid >> 4) * LDW + c) = o;
  }
  __syncthreads();

  // ---- MFMA phase: wave t computes cols [16t, 16t+16) of the 16x64 tile ----
  {
    const int wave = tid >> 6;
    const int lane = tid & 63;
    const int quad = lane >> 4;
    const int cg = lane & 15;
    floatx4 acc = (floatx4){0.f, 0.f, 0.f, 0.f};
    const unsigned short* wrow = w2t + (size_t)(wave * 16 + cg) * K;
    const unsigned short* arow = hl + cg * LDW;
#pragma unroll
    for (int kb = 0; kb < 4; ++kb) {
      short8 afr = *(const short8*)(arow + kb * 32 + quad * 8);
      short8 bfr = *(const short8*)(wrow + kb * 32 + quad * 8);
      acc = __builtin_amdgcn_mfma_f32_16x16x32_bf16(afr, bfr, acc, 0, 0, 0);
    }
    float4 dv4 = *(const float4*)(dis + row0 + quad * 4);
    float dvs[4] = {dv4.x, dv4.y, dv4.z, dv4.w};
#pragma unroll
    for (int r = 0; r < 4; ++r)
      obuf[(quad * 4 + r) * LDO + wave * 16 + cg] = bf16u(acc[r] * dvs[r]);
  }
  __syncthreads();

  if (tid < 128) {
    int r = tid >> 3;
    int cid = tid & 7;
    uint4 u = *(const uint4*)(obuf + r * LDO + cid * 8);
    *(uint4*)(g2 + (size_t)(row0 + r) * D_H2 + cid * 8) = u;
  }
}

// ---- Fused layer-2 gather + ReLU + MFMA head + softmax. g bf16 (F=64).
__global__ __launch_bounds__(256) void gather2_final_kernel(
    const unsigned short* __restrict__ g, const int* __restrict__ col,
    const int* __restrict__ row_ptr, const float* __restrict__ dis,
    const float* __restrict__ b2, const float* __restrict__ Wf,
    const float* __restrict__ bf, float* __restrict__ out, int n) {
  constexpr int LDH = 72;  // bf16 stride: 144B, 16B-aligned
  __shared__ unsigned short ha[32 * LDH];   // h2 tile bf16
  __shared__ unsigned short wtf[16 * LDH];  // Wf^T bf16, padded N=16
  __shared__ float bfs[D_O];
  __shared__ float ls[32][12];
  const int tid = threadIdx.x;
  if (tid < 128) {
    int nn = tid >> 3;
    int k = (tid & 7) * 8;
    uint4 u;
    if (nn < D_O) {
      u.x = pack_bf2(Wf[(size_t)(k + 0) * D_O + nn], Wf[(size_t)(k + 1) * D_O + nn]);
      u.y = pack_bf2(Wf[(size_t)(k + 2) * D_O + nn], Wf[(size_t)(k + 3) * D_O + nn]);
      u.z = pack_bf2(Wf[(size_t)(k + 4) * D_O + nn], Wf[(size_t)(k + 5) * D_O + nn]);
      u.w = pack_bf2(Wf[(size_t)(k + 6) * D_O + nn], Wf[(size_t)(k + 7) * D_O + nn]);
    } else {
      u = make_uint4(0u, 0u, 0u, 0u);
    }
    *(uint4*)(wtf + nn * LDH + k) = u;
  }
  if (tid < D_O) bfs[tid] = bf[tid];

  const int gid = blockIdx.x * 256 + tid;
  const int v = gid >> 3;
  const int nl = tid >> 3;
  const int c = (tid & 7) * 8;
  if (v < n) {
    int start = row_ptr[v];
    int end = row_ptr[v + 1];
    float acc[8];
#pragma unroll
    for (int q = 0; q < 8; ++q) acc[q] = 0.f;
    acc_u4(acc, *(const uint4*)(g + (size_t)v * D_H2 + c));  // self-loop
    int e = start;
    for (; e + 4 <= end; e += 4) {
      int s0 = col[e + 0], s1 = col[e + 1], s2 = col[e + 2], s3 = col[e + 3];
      uint4 u0 = *(const uint4*)(g + (size_t)s0 * D_H2 + c);
      uint4 u1 = *(const uint4*)(g + (size_t)s1 * D_H2 + c);
      uint4 u2 = *(const uint4*)(g + (size_t)s2 * D_H2 + c);
      uint4 u3 = *(const uint4*)(g + (size_t)s3 * D_H2 + c);
      acc_u4(acc, u0); acc_u4(acc, u1); acc_u4(acc, u2); acc_u4(acc, u3);
    }
    for (; e < end; ++e) {
      uint4 u = *(const uint4*)(g + (size_t)col[e] * D_H2 + c);
      acc_u4(acc, u);
    }
    float dv = dis[v];
    float4 bv0 = *(const float4*)(b2 + c);
    float4 bv1 = *(const float4*)(b2 + c + 4);
    float r0 = fmaxf(dv * acc[0] + bv0.x, 0.f);
    float r1 = fmaxf(dv * acc[1] + bv0.y, 0.f);
    float r2 = fmaxf(dv * acc[2] + bv0.z, 0.f);
    float r3 = fmaxf(dv * acc[3] + bv0.w, 0.f);
    float r4 = fmaxf(dv * acc[4] + bv1.x, 0.f);
    float r5 = fmaxf(dv * acc[5] + bv1.y, 0.f);
    float r6 = fmaxf(dv * acc[6] + bv1.z, 0.f);
    float r7 = fmaxf(dv * acc[7] + bv1.w, 0.f);
    uint4 o;
    o.x = pack_bf2(r0, r1);
    o.y = pack_bf2(r2, r3);
    o.z = pack_bf2(r4, r5);
    o.w = pack_bf2(r6, r7);
    *(uint4*)(ha + nl * LDH + c) = o;
  }
  __syncthreads();
  // ---- MFMA head: waves 0/1 -> 16 nodes x 16 classes each (K=64) ----
  {
    const int wave = tid >> 6;
    if (wave < 2) {
      const int lane = tid & 63;
      const int quad = lane >> 4;
      const int cg = lane & 15;
      floatx4 acc = (floatx4){0.f, 0.f, 0.f, 0.f};
      const unsigned short* arow = ha + (wave * 16 + cg) * LDH;
      const unsigned short* wrow = wtf + cg * LDH;
#pragma unroll
      for (int kb = 0; kb < 2; ++kb) {
        short8 afr = *(const short8*)(arow + kb * 32 + quad * 8);
        short8 bfr = *(const short8*)(wrow + kb * 32 + quad * 8);
        acc = __builtin_amdgcn_mfma_f32_16x16x32_bf16(afr, bfr, acc, 0, 0, 0);
      }
      if (cg < D_O) {
        float bb = bfs[cg];
#pragma unroll
        for (int r = 0; r < 4; ++r)
          ls[wave * 16 + quad * 4 + r][cg] = acc[r] + bb;
      }
    }
  }
  __syncthreads();
  if (tid < 32) {
    int v2 = blockIdx.x * 32 + tid;
    if (v2 < n) {
      float m = ls[tid][0];
#pragma unroll
      for (int j = 1; j < D_O; ++j) m = fmaxf(m, ls[tid][j]);
      float s = 0.f;
      float ex[D_O];
#pragma unroll
      for (int j = 0; j < D_O; ++j) { ex[j] = expf(ls[tid][j] - m); s += ex[j]; }
      float inv = 1.0f / s;
#pragma unroll
      for (int j = 0; j < D_O; ++j) ls[tid][j] = ex[j] * inv;
    }
  }
  __syncthreads();
  for (int idx = tid; idx < 32 * D_O; idx += 256) {
    int gidx = blockIdx.x * 32 * D_O + idx;
    if (gidx < n * D_O) out[gidx] = ls[idx / D_O][idx % D_O];
  }
}

extern "C" void kernel_launch(void* const* d_in, const int* in_sizes, int n_in,
                              void* d_out, int out_size, void* d_ws, size_t ws_size,
                              hipStream_t stream) {
  const float* x  = (const float*)d_in[0];
  const int*   ei = (const int*)d_in[1];
  const float* W1 = (const float*)d_in[2];
  const float* b1 = (const float*)d_in[3];
  const float* W2 = (const float*)d_in[4];
  const float* b2 = (const float*)d_in[5];
  const float* Wf = (const float*)d_in[6];
  const float* bf = (const float*)d_in[7];
  float* out = (float*)d_out;

  const int E = in_sizes[1] / 2;
  const int* src = ei;
  const int* dst = ei + E;

  char* ws = (char*)d_ws;
  unsigned short* g1 = (unsigned short*)(ws + OFF_G1);
  unsigned short* g2 = (unsigned short*)(ws + OFF_G2);
  unsigned short* w1t = (unsigned short*)(ws + OFF_W1T);
  unsigned short* w2t = (unsigned short*)(ws + OFF_W2T);
  unsigned int* part = (unsigned int*)(ws + OFF_PART);
  int*   col     = (int*)(ws + OFF_COL);
  float* dis     = (float*)(ws + OFF_DIS);
  int*   row_ptr = (int*)(ws + OFF_ROWPTR);
  int*   H       = (int*)(ws + OFF_HIST);
  int*   total   = (int*)(ws + OFF_TOT);

  const int nchunk = (E + ECH - 1) / ECH;  // 391

  // ---- CSR build: counting sort, zero global atomics, all writes coalesced
  // (histo also pre-packs W1^T/W2^T bf16 into workspace)
  histo_kernel<<<nchunk, 256, 0, stream>>>(dst, H, E, nchunk, W1, W2, w1t, w2t);
  bucket_scan_kernel<<<NB, 256, 0, stream>>>(H, total, nchunk);
  scatter_kernel<<<nchunk, 256, 0, stream>>>(src, dst, H, total, part, E, nchunk);
  bucket_csr_kernel<<<NB, 256, 0, stream>>>(part, total, row_ptr, dis, col, NN, E);

  // ---- layer 1 GEMM ----
  gemm_mfma_kernel<D_H1>
      <<<(NN + 63) / 64, 256, 0, stream>>>(x, w1t, dis, g1, NN);

  // ---- fused gather1 + ReLU + gemm2 ----
  gather1_gemm2_kernel<<<NN / 16, 256, 0, stream>>>(
      g1, col, row_ptr, dis, b1, w2t, g2, NN);

  // ---- fused gather2 + MFMA head + softmax ----
  gather2_final_kernel<<<(NN + 31) / 32, 256, 0, stream>>>(
      g2, col, row_ptr, dis, b2, Wf, bf, out, NN);
}

// Round 2
// 243.926 us; speedup vs baseline: 1.0835x; 1.0835x over previous
//
#include <hip/hip_runtime.h>
#include <math.h>

#define NN 100000
#define D_IN 128
#define D_H1 128
#define D_H2 64
#define D_O 10
#define NB 256          // node buckets for counting-sort CSR build
#define BDIV 391        // bucket(d) = d / 391  (255*391 = 99705 <= d < 100000 -> 255)
#define ECH 4096        // edges per chunk (histo/scatter)
#define COLCAP 8192     // LDS col capacity per bucket (mean 6250, sigma 79 -> +24s)
#define S_SEG 16        // src segments per adjacency list (segment = 1.6MB of g1)
#define SEGW 6250       // nodes per src segment

// ---- workspace layout (bytes) ----
static const size_t OFF_G1     = 0;                 // N*128 bf16 = 25.6 MB
static const size_t OFF_G2     = 25600000;          // N*64 bf16 = 12.8 MB
static const size_t OFF_W1T    = 40000000;          // 128*128 bf16 = 32 KB (pre-packed W1^T)
static const size_t OFF_W2T    = 40100000;          // 64*128 bf16 = 16 KB (pre-packed W2^T)
static const size_t OFF_PART   = 76800000;          // E uint32 = 6.4 MB (packed d_local|src)
static const size_t OFF_COL    = 102400000;         // E int32 = 6.4 MB
static const size_t OFF_DIS    = 108800000;         // N f32
static const size_t OFF_ROWPTR = 109300000;         // (N+1) int32
static const size_t OFF_HIST   = 109800000;         // NB * nchunk int32 (~400 KB)
static const size_t OFF_TOT    = 110700000;         // NB int32

typedef __attribute__((ext_vector_type(8))) short short8;
typedef __attribute__((ext_vector_type(4))) float floatx4;

// ---- bf16 helpers (RNE; values are finite) ----
__device__ inline unsigned int pack_bf2(float a, float b) {
  unsigned int ua = __float_as_uint(a);
  ua += 0x7fffu + ((ua >> 16) & 1u);
  unsigned int ub = __float_as_uint(b);
  ub += 0x7fffu + ((ub >> 16) & 1u);
  return (ua >> 16) | (ub & 0xffff0000u);
}
__device__ inline unsigned short bf16u(float a) {
  unsigned int ua = __float_as_uint(a);
  ua += 0x7fffu + ((ua >> 16) & 1u);
  return (unsigned short)(ua >> 16);
}
__device__ inline float bflo(unsigned int u) { return __uint_as_float(u << 16); }
__device__ inline float bfhi(unsigned int u) { return __uint_as_float(u & 0xffff0000u); }
__device__ inline short8 as_short8(uint4 u) {
  union { uint4 u4; short8 s8; } c; c.u4 = u; return c.s8;
}
__device__ inline void acc_u4(float* acc, uint4 u) {
  acc[0] += bflo(u.x); acc[1] += bfhi(u.x);
  acc[2] += bflo(u.y); acc[3] += bfhi(u.y);
  acc[4] += bflo(u.z); acc[5] += bfhi(u.z);
  acc[6] += bflo(u.w); acc[7] += bfhi(u.w);
}

// ---- 1. per-chunk bucket histogram: H[b][c] (LDS atomics only) ----
// Also folds the one-time weight transpose+bf16 pack into the first 96 blocks.
__global__ __launch_bounds__(256) void histo_kernel(
    const int* __restrict__ dst, int* __restrict__ H, int E, int nchunk,
    const float* __restrict__ W1, const float* __restrict__ W2,
    unsigned short* __restrict__ w1t, unsigned short* __restrict__ w2t) {
  __shared__ int hist[NB];
  const int tid = threadIdx.x;
  hist[tid] = 0;
  __syncthreads();
  const int e0 = blockIdx.x * ECH;
#pragma unroll
  for (int i = 0; i < ECH / 256; ++i) {
    int e = e0 + i * 256 + tid;
    if (e < E) atomicAdd(&hist[dst[e] / BDIV], 1);
  }
  __syncthreads();
  H[tid * nchunk + blockIdx.x] = hist[tid];
  // one-time weight pack (nchunk = 391 >= 96 for this problem size)
  if (blockIdx.x < 64) {            // W1^T: [128][128] bf16
    int o = blockIdx.x * 256 + tid;
    int nn = o >> 7, k = o & 127;
    w1t[o] = bf16u(W1[(size_t)k * D_H1 + nn]);
  } else if (blockIdx.x < 96) {     // W2^T: [64][128] bf16
    int o = (blockIdx.x - 64) * 256 + tid;
    int nn = o >> 7, k = o & 127;
    w2t[o] = bf16u(W2[(size_t)k * D_H2 + nn]);
  }
}

// ---- 2. per-bucket exclusive scan over chunks (in place) + bucket totals ----
__global__ __launch_bounds__(256) void bucket_scan_kernel(
    int* __restrict__ H, int* __restrict__ total, int nchunk) {
  __shared__ int sm[256];
  const int tid = threadIdx.x;
  int* row = H + (size_t)blockIdx.x * nchunk;
  int carry = 0;
  for (int t0 = 0; t0 < nchunk; t0 += 256) {
    int idx = t0 + tid;
    int v = (idx < nchunk) ? row[idx] : 0;
    sm[tid] = v;
    __syncthreads();
#pragma unroll
    for (int off = 1; off < 256; off <<= 1) {
      int t2 = (tid >= off) ? sm[tid - off] : 0;
      __syncthreads();
      sm[tid] += t2;
      __syncthreads();
    }
    int incl = sm[tid];
    int ttot = sm[255];
    __syncthreads();  // all reads done before next-tile overwrite
    if (idx < nchunk) row[idx] = carry + incl - v;
    carry += ttot;
  }
  if (tid == 0) total[blockIdx.x] = carry;
}

// ---- 3. deterministic scatter into bucket segments (LDS rank, NO global atomics).
// part entry packed: (d_local << 17) | src  (src < 2^17, d_local < 391).
__global__ __launch_bounds__(256) void scatter_kernel(
    const int* __restrict__ src, const int* __restrict__ dst,
    const int* __restrict__ H, const int* __restrict__ total,
    unsigned int* __restrict__ part, int E, int nchunk) {
  __shared__ int sm[NB];
  __shared__ int offs_s[NB];
  __shared__ int base_s[NB];
  __shared__ int cnt[NB];
  const int tid = threadIdx.x;
  // inline exclusive scan of totals -> base_s
  {
    int v = total[tid];
    sm[tid] = v;
    __syncthreads();
#pragma unroll
    for (int off = 1; off < 256; off <<= 1) {
      int t2 = (tid >= off) ? sm[tid - off] : 0;
      __syncthreads();
      sm[tid] += t2;
      __syncthreads();
    }
    base_s[tid] = sm[tid] - v;
  }
  offs_s[tid] = H[tid * nchunk + blockIdx.x];
  cnt[tid] = 0;
  __syncthreads();
  const int e0 = blockIdx.x * ECH;
#pragma unroll
  for (int i = 0; i < ECH / 256; ++i) {
    int e = e0 + i * 256 + tid;
    if (e < E) {
      int d = dst[e];
      int s = src[e];
      int b = d / BDIV;
      int r = atomicAdd(&cnt[b], 1);  // LDS only
      unsigned int p = ((unsigned int)(d - b * BDIV) << 17) | (unsigned int)s;
      part[(size_t)base_s[b] + offs_s[b] + r] = p;
    }
  }
}

// ---- 4. per-bucket CSR finalize with SRC-SEGMENT SORT.
// col within each adjacency list is ordered by src/SEGW (16 segments). All
// gather blocks then sweep src-space monotonically in near-lockstep, so the
// instantaneous g1 working set (~3MB) fits each XCD's 4MB L2 -> L2 misses of
// the random gather collapse. Per-(d_local,seg) counters (6256) scanned with
// a wave-shuffle scan (14 barriers total, not 400).
__global__ __launch_bounds__(256) void bucket_csr_kernel(
    const unsigned int* __restrict__ part, const int* __restrict__ total,
    int* __restrict__ row_ptr, float* __restrict__ dis,
    int* __restrict__ col, int n, int E) {
  constexpr int TOT = BDIV * S_SEG;  // 6256
  __shared__ int sm[256];
  __shared__ int cnt2[TOT + 1];      // counts -> exclusive offsets -> cursors
  __shared__ int col_s[COLCAP];
  __shared__ int wsum[4];
  __shared__ int ebase_s, ecnt_s;
  const int tid = threadIdx.x;
  const int b = blockIdx.x;
  const int lo = b * BDIV;
  const int nn = min(n - lo, BDIV);
  // inline scan of totals for this bucket's base
  {
    int v = total[tid];
    sm[tid] = v;
    __syncthreads();
#pragma unroll
    for (int off = 1; off < 256; off <<= 1) {
      int t2 = (tid >= off) ? sm[tid - off] : 0;
      __syncthreads();
      sm[tid] += t2;
      __syncthreads();
    }
    if (tid == b) { ebase_s = sm[tid] - v; ecnt_s = v; }
  }
  for (int t = tid; t <= TOT; t += 256) cnt2[t] = 0;
  __syncthreads();
  const int ebase = ebase_s;
  const int ecnt = ecnt_s;
  // P1: per-(node,seg) count (LDS atomics)
  for (int i0 = 0; i0 < ecnt; i0 += 256) {
    int idx = i0 + tid;
    if (idx < ecnt) {
      unsigned int p = part[ebase + idx];
      int s = (int)(p & 0x1FFFFu);
      atomicAdd(&cnt2[(int)(p >> 17) * S_SEG + s / SEGW], 1);
    }
  }
  __syncthreads();
  // P2: in-place exclusive scan of cnt2[0..TOT) via wave-shuffle scan
  {
    const int lane = tid & 63;
    const int wv = tid >> 6;
    int carry = 0;
    for (int t0 = 0; t0 < TOT; t0 += 1024) {
      int i0 = t0 + tid * 4;
      int v0 = (i0 + 0 < TOT) ? cnt2[i0 + 0] : 0;
      int v1 = (i0 + 1 < TOT) ? cnt2[i0 + 1] : 0;
      int v2 = (i0 + 2 < TOT) ? cnt2[i0 + 2] : 0;
      int v3 = (i0 + 3 < TOT) ? cnt2[i0 + 3] : 0;
      int ts = v0 + v1 + v2 + v3;
      int incl = ts;
#pragma unroll
      for (int off = 1; off < 64; off <<= 1) {
        int o = __shfl_up(incl, off);
        if (lane >= off) incl += o;
      }
      if (lane == 63) wsum[wv] = incl;
      __syncthreads();
      int wpre = 0;
#pragma unroll
      for (int w = 0; w < 4; ++w)
        if (w < wv) wpre += wsum[w];
      int btot = wsum[0] + wsum[1] + wsum[2] + wsum[3];
      int e = carry + wpre + (incl - ts);
      __syncthreads();  // wsum reads done before next-tile writes
      if (i0 + 0 < TOT) cnt2[i0 + 0] = e;
      if (i0 + 1 < TOT) cnt2[i0 + 1] = e + v0;
      if (i0 + 2 < TOT) cnt2[i0 + 2] = e + v0 + v1;
      if (i0 + 3 < TOT) cnt2[i0 + 3] = e + v0 + v1 + v2;
      carry += btot;
    }
    if (tid == 0) cnt2[TOT] = carry;
  }
  __syncthreads();
  // row_ptr + dis from pristine offsets (before cursors get bumped)
  for (int t = tid; t < nn; t += 256) {
    int b0 = cnt2[t * S_SEG];
    int b1 = cnt2[(t + 1) * S_SEG];
    row_ptr[lo + t] = ebase + b0;
    dis[lo + t] = rsqrtf((float)(b1 - b0) + 1.0f);
  }
  if (b == NB - 1 && tid == 0) row_ptr[n] = E;
  __syncthreads();  // all offset reads done before P3 mutates cnt2
  // P3: bin srcs into LDS col by (node,seg) -> src-segment-sorted lists
  for (int i0 = 0; i0 < ecnt; i0 += 256) {
    int idx = i0 + tid;
    if (idx < ecnt) {
      unsigned int p = part[ebase + idx];
      int s = (int)(p & 0x1FFFFu);
      int r = atomicAdd(&cnt2[(int)(p >> 17) * S_SEG + s / SEGW], 1);
      if (r < COLCAP) col_s[r] = s;
    }
  }
  __syncthreads();
  // P4: coalesced col writeback
  const int m = min(ecnt, COLCAP);
  for (int idx = tid; idx < m; idx += 256) col[ebase + idx] = col_s[idx];
}

// ---- MFMA GEMM (layer 1): out = bf16(dis * (A_f32 @ W)), K=128.
// W staged LDS from pre-packed bf16 w1t (coalesced uint4); buf aliases wt
// (phases barrier-separated) -> LDS 34.8KB -> 4 blocks/CU.
template <int NOUT>
__global__ __launch_bounds__(256) void gemm_mfma_kernel(
    const float* __restrict__ A_, const unsigned short* __restrict__ w1t,
    const float* __restrict__ dis, unsigned short* __restrict__ out, int nrows) {
  constexpr int K = 128;
  constexpr int NT = NOUT / 16;
  constexpr int LDW = K + 8;  // 272B row stride: 16B-aligned, b128 conflict-free
  __shared__ unsigned short wt[NOUT * LDW];
  unsigned short* buf = wt;  // reused after barrier (4*16*LDW <= NOUT*LDW)
  const int tid = threadIdx.x;

  // stage W^T bf16 -> LDS, coalesced
  {
    const uint4* wsrc = (const uint4*)w1t;  // NOUT*K shorts = NOUT*16 uint4
#pragma unroll
    for (int j = 0; j < NOUT * K / (8 * 256); ++j) {
      int o = tid + j * 256;
      int row = o >> 4;
      int k8 = (o & 15) * 8;
      *(uint4*)(wt + row * LDW + k8) = wsrc[o];
    }
  }

  const int wave = tid >> 6;
  const int lane = tid & 63;
  const int quad = lane >> 4;
  const int cg = lane & 15;
  const int row0w = blockIdx.x * 64 + wave * 16;

  short8 afr[4];
  {
    int row = row0w + cg;
    if (row > nrows - 1) row = nrows - 1;  // clamp: garbage rows never stored
#pragma unroll
    for (int kb = 0; kb < 4; ++kb) {
      const float* p = A_ + (size_t)row * K + kb * 32 + quad * 8;
      float4 v0 = *(const float4*)(p);
      float4 v1 = *(const float4*)(p + 4);
      uint4 u;
      u.x = pack_bf2(v0.x, v0.y); u.y = pack_bf2(v0.z, v0.w);
      u.z = pack_bf2(v1.x, v1.y); u.w = pack_bf2(v1.z, v1.w);
      afr[kb] = as_short8(u);
    }
  }
  __syncthreads();

  floatx4 acc[NT];
#pragma unroll
  for (int t = 0; t < NT; ++t) acc[t] = (floatx4){0.f, 0.f, 0.f, 0.f};
#pragma unroll
  for (int t = 0; t < NT; ++t) {
    const unsigned short* wrow = wt + (t * 16 + cg) * LDW;
#pragma unroll
    for (int kb = 0; kb < 4; ++kb) {
      short8 bfr = *(const short8*)(wrow + kb * 32 + quad * 8);
      acc[t] = __builtin_amdgcn_mfma_f32_16x16x32_bf16(afr[kb], bfr, acc[t], 0, 0, 0);
    }
  }
  __syncthreads();  // all wt reads done before reuse as buf

  float4 dv4 = *(const float4*)(dis + row0w + quad * 4);  // OOB-safe: ws slack
  float dvs[4] = {dv4.x, dv4.y, dv4.z, dv4.w};
  unsigned short* mybuf = buf + wave * 16 * LDW;
#pragma unroll
  for (int t = 0; t < NT; ++t)
#pragma unroll
    for (int r = 0; r < 4; ++r)
      mybuf[(quad * 4 + r) * LDW + t * 16 + cg] = bf16u(acc[t][r] * dvs[r]);
  __syncthreads();

  constexpr int CHUNKS = NOUT / 8;
  constexpr int RPI = 64 / CHUNKS;
  int cid = lane % CHUNKS;
  int rs = lane / CHUNKS;
#pragma unroll
  for (int i = 0; i < 16 / RPI; ++i) {
    int r = rs + i * RPI;
    int grow = row0w + r;
    if (grow < nrows) {
      uint4 u = *(const uint4*)(mybuf + r * LDW + cid * 8);
      *(uint4*)(out + (size_t)grow * NOUT + cid * 8) = u;
    }
  }
}

// ---- Fused layer-1 gather + ReLU + gemm2 (h1 @ W2, MFMA) -> g2.
// Block = 16 nodes; grid = NN/16 exactly. W2^T staged LDS from pre-packed bf16
// (coalesced uint4, no transposed f32 reads). col lists are src-sorted ->
// all blocks sweep g1 monotonically -> L2-resident slice.
__global__ __launch_bounds__(256) void gather1_gemm2_kernel(
    const unsigned short* __restrict__ g, const int* __restrict__ col,
    const int* __restrict__ row_ptr, const float* __restrict__ dis,
    const float* __restrict__ b1, const unsigned short* __restrict__ w2t,
    unsigned short* __restrict__ g2, int n) {
  constexpr int K = D_H1;        // 128
  constexpr int LDW = K + 8;     // 136
  constexpr int LDO = 80;        // 160B row stride: 16B-aligned
  __shared__ unsigned short wt[D_H2 * LDW];   // W2^T bf16, 17.4 KB
  __shared__ unsigned short hl[16 * LDW];     // h tile bf16, 4.4 KB
  __shared__ unsigned short obuf[16 * LDO];   // out tile, 2.56 KB
  const int tid = threadIdx.x;
  const int row0 = blockIdx.x * 16;

  // stage W2^T bf16 -> LDS, coalesced (1024 uint4)
  {
    const uint4* wsrc = (const uint4*)w2t;
#pragma unroll
    for (int j = 0; j < 4; ++j) {
      int o = tid + j * 256;
      int row = o >> 4;
      int k8 = (o & 15) * 8;
      *(uint4*)(wt + row * LDW + k8) = wsrc[o];
    }
  }

  // ---- gather phase: 16 nodes x 16 lanes x 8 feats ----
  {
    const int v = row0 + (tid >> 4);
    const int c = (tid & 15) * 8;
    const int start = row_ptr[v];
    const int end = row_ptr[v + 1];
    float acc[8];
#pragma unroll
    for (int q = 0; q < 8; ++q) acc[q] = 0.f;
    acc_u4(acc, *(const uint4*)(g + (size_t)v * K + c));  // self-loop
    int e = start;
    for (; e + 4 <= end; e += 4) {
      int s0 = col[e + 0], s1 = col[e + 1], s2 = col[e + 2], s3 = col[e + 3];
      uint4 u0 = *(const uint4*)(g + (size_t)s0 * K + c);
      uint4 u1 = *(const uint4*)(g + (size_t)s1 * K + c);
      uint4 u2 = *(const uint4*)(g + (size_t)s2 * K + c);
      uint4 u3 = *(const uint4*)(g + (size_t)s3 * K + c);
      acc_u4(acc, u0); acc_u4(acc, u1); acc_u4(acc, u2); acc_u4(acc, u3);
    }
    for (; e < end; ++e) {
      uint4 u = *(const uint4*)(g + (size_t)col[e] * K + c);
      acc_u4(acc, u);
    }
    float dv = dis[v];
    float4 bv0 = *(const float4*)(b1 + c);
    float4 bv1 = *(const float4*)(b1 + c + 4);
    float r0 = fmaxf(dv * acc[0] + bv0.x, 0.f);
    float r1 = fmaxf(dv * acc[1] + bv0.y, 0.f);
    float r2 = fmaxf(dv * acc[2] + bv0.z, 0.f);
    float r3 = fmaxf(dv * acc[3] + bv0.w, 0.f);
    float r4 = fmaxf(dv * acc[4] + bv1.x, 0.f);
    float r5 = fmaxf(dv * acc[5] + bv1.y, 0.f);
    float r6 = fmaxf(dv * acc[6] + bv1.z, 0.f);
    float r7 = fmaxf(dv * acc[7] + bv1.w, 0.f);
    uint4 o;
    o.x = pack_bf2(r0, r1);
    o.y = pack_bf2(r2, r3);
    o.z = pack_bf2(r4, r5);
    o.w = pack_bf2(r6, r7);
    *(uint4*)(hl + (tid >> 4) * LDW + c) = o;
  }
  __syncthreads();

  // ---- MFMA phase: wave t computes cols [16t, 16t+16) of the 16x64 tile ----
  {
    const int wave = tid >> 6;
    const int lane = tid & 63;
    const int quad = lane >> 4;
    const int cg = lane & 15;
    floatx4 acc = (floatx4){0.f, 0.f, 0.f, 0.f};
    const unsigned short* wrow = wt + (wave * 16 + cg) * LDW;
    const unsigned short* arow = hl + cg * LDW;
#pragma unroll
    for (int kb = 0; kb < 4; ++kb) {
      short8 afr = *(const short8*)(arow + kb * 32 + quad * 8);
      short8 bfr = *(const short8*)(wrow + kb * 32 + quad * 8);
      acc = __builtin_amdgcn_mfma_f32_16x16x32_bf16(afr, bfr, acc, 0, 0, 0);
    }
    float4 dv4 = *(const float4*)(dis + row0 + quad * 4);
    float dvs[4] = {dv4.x, dv4.y, dv4.z, dv4.w};
#pragma unroll
    for (int r = 0; r < 4; ++r)
      obuf[(quad * 4 + r) * LDO + wave * 16 + cg] = bf16u(acc[r] * dvs[r]);
  }
  __syncthreads();

  if (tid < 128) {
    int r = tid >> 3;
    int cid = tid & 7;
    uint4 u = *(const uint4*)(obuf + r * LDO + cid * 8);
    *(uint4*)(g2 + (size_t)(row0 + r) * D_H2 + cid * 8) = u;
  }
}

// ---- Fused layer-2 gather + ReLU + MFMA head + softmax. g bf16 (F=64).
__global__ __launch_bounds__(256) void gather2_final_kernel(
    const unsigned short* __restrict__ g, const int* __restrict__ col,
    const int* __restrict__ row_ptr, const float* __restrict__ dis,
    const float* __restrict__ b2, const float* __restrict__ Wf,
    const float* __restrict__ bf, float* __restrict__ out, int n) {
  constexpr int LDH = 72;  // bf16 stride: 144B, 16B-aligned
  __shared__ unsigned short ha[32 * LDH];   // h2 tile bf16
  __shared__ unsigned short wtf[16 * LDH];  // Wf^T bf16, padded N=16
  __shared__ float bfs[D_O];
  __shared__ float ls[32][12];
  const int tid = threadIdx.x;
  if (tid < 128) {
    int nn = tid >> 3;
    int k = (tid & 7) * 8;
    uint4 u;
    if (nn < D_O) {
      u.x = pack_bf2(Wf[(size_t)(k + 0) * D_O + nn], Wf[(size_t)(k + 1) * D_O + nn]);
      u.y = pack_bf2(Wf[(size_t)(k + 2) * D_O + nn], Wf[(size_t)(k + 3) * D_O + nn]);
      u.z = pack_bf2(Wf[(size_t)(k + 4) * D_O + nn], Wf[(size_t)(k + 5) * D_O + nn]);
      u.w = pack_bf2(Wf[(size_t)(k + 6) * D_O + nn], Wf[(size_t)(k + 7) * D_O + nn]);
    } else {
      u = make_uint4(0u, 0u, 0u, 0u);
    }
    *(uint4*)(wtf + nn * LDH + k) = u;
  }
  if (tid < D_O) bfs[tid] = bf[tid];

  const int gid = blockIdx.x * 256 + tid;
  const int v = gid >> 3;
  const int nl = tid >> 3;
  const int c = (tid & 7) * 8;
  if (v < n) {
    int start = row_ptr[v];
    int end = row_ptr[v + 1];
    float acc[8];
#pragma unroll
    for (int q = 0; q < 8; ++q) acc[q] = 0.f;
    acc_u4(acc, *(const uint4*)(g + (size_t)v * D_H2 + c));  // self-loop
    int e = start;
    for (; e + 4 <= end; e += 4) {
      int s0 = col[e + 0], s1 = col[e + 1], s2 = col[e + 2], s3 = col[e + 3];
      uint4 u0 = *(const uint4*)(g + (size_t)s0 * D_H2 + c);
      uint4 u1 = *(const uint4*)(g + (size_t)s1 * D_H2 + c);
      uint4 u2 = *(const uint4*)(g + (size_t)s2 * D_H2 + c);
      uint4 u3 = *(const uint4*)(g + (size_t)s3 * D_H2 + c);
      acc_u4(acc, u0); acc_u4(acc, u1); acc_u4(acc, u2); acc_u4(acc, u3);
    }
    for (; e < end; ++e) {
      uint4 u = *(const uint4*)(g + (size_t)col[e] * D_H2 + c);
      acc_u4(acc, u);
    }
    float dv = dis[v];
    float4 bv0 = *(const float4*)(b2 + c);
    float4 bv1 = *(const float4*)(b2 + c + 4);
    float r0 = fmaxf(dv * acc[0] + bv0.x, 0.f);
    float r1 = fmaxf(dv * acc[1] + bv0.y, 0.f);
    float r2 = fmaxf(dv * acc[2] + bv0.z, 0.f);
    float r3 = fmaxf(dv * acc[3] + bv0.w, 0.f);
    float r4 = fmaxf(dv * acc[4] + bv1.x, 0.f);
    float r5 = fmaxf(dv * acc[5] + bv1.y, 0.f);
    float r6 = fmaxf(dv * acc[6] + bv1.z, 0.f);
    float r7 = fmaxf(dv * acc[7] + bv1.w, 0.f);
    uint4 o;
    o.x = pack_bf2(r0, r1);
    o.y = pack_bf2(r2, r3);
    o.z = pack_bf2(r4, r5);
    o.w = pack_bf2(r6, r7);
    *(uint4*)(ha + nl * LDH + c) = o;
  }
  __syncthreads();
  // ---- MFMA head: waves 0/1 -> 16 nodes x 16 classes each (K=64) ----
  {
    const int wave = tid >> 6;
    if (wave < 2) {
      const int lane = tid & 63;
      const int quad = lane >> 4;
      const int cg = lane & 15;
      floatx4 acc = (floatx4){0.f, 0.f, 0.f, 0.f};
      const unsigned short* arow = ha + (wave * 16 + cg) * LDH;
      const unsigned short* wrow = wtf + cg * LDH;
#pragma unroll
      for (int kb = 0; kb < 2; ++kb) {
        short8 afr = *(const short8*)(arow + kb * 32 + quad * 8);
        short8 bfr = *(const short8*)(wrow + kb * 32 + quad * 8);
        acc = __builtin_amdgcn_mfma_f32_16x16x32_bf16(afr, bfr, acc, 0, 0, 0);
      }
      if (cg < D_O) {
        float bb = bfs[cg];
#pragma unroll
        for (int r = 0; r < 4; ++r)
          ls[wave * 16 + quad * 4 + r][cg] = acc[r] + bb;
      }
    }
  }
  __syncthreads();
  if (tid < 32) {
    int v2 = blockIdx.x * 32 + tid;
    if (v2 < n) {
      float m = ls[tid][0];
#pragma unroll
      for (int j = 1; j < D_O; ++j) m = fmaxf(m, ls[tid][j]);
      float s = 0.f;
      float ex[D_O];
#pragma unroll
      for (int j = 0; j < D_O; ++j) { ex[j] = expf(ls[tid][j] - m); s += ex[j]; }
      float inv = 1.0f / s;
#pragma unroll
      for (int j = 0; j < D_O; ++j) ls[tid][j] = ex[j] * inv;
    }
  }
  __syncthreads();
  for (int idx = tid; idx < 32 * D_O; idx += 256) {
    int gidx = blockIdx.x * 32 * D_O + idx;
    if (gidx < n * D_O) out[gidx] = ls[idx / D_O][idx % D_O];
  }
}

extern "C" void kernel_launch(void* const* d_in, const int* in_sizes, int n_in,
                              void* d_out, int out_size, void* d_ws, size_t ws_size,
                              hipStream_t stream) {
  const float* x  = (const float*)d_in[0];
  const int*   ei = (const int*)d_in[1];
  const float* W1 = (const float*)d_in[2];
  const float* b1 = (const float*)d_in[3];
  const float* W2 = (const float*)d_in[4];
  const float* b2 = (const float*)d_in[5];
  const float* Wf = (const float*)d_in[6];
  const float* bf = (const float*)d_in[7];
  float* out = (float*)d_out;

  const int E = in_sizes[1] / 2;
  const int* src = ei;
  const int* dst = ei + E;

  char* ws = (char*)d_ws;
  unsigned short* g1 = (unsigned short*)(ws + OFF_G1);
  unsigned short* g2 = (unsigned short*)(ws + OFF_G2);
  unsigned short* w1t = (unsigned short*)(ws + OFF_W1T);
  unsigned short* w2t = (unsigned short*)(ws + OFF_W2T);
  unsigned int* part = (unsigned int*)(ws + OFF_PART);
  int*   col     = (int*)(ws + OFF_COL);
  float* dis     = (float*)(ws + OFF_DIS);
  int*   row_ptr = (int*)(ws + OFF_ROWPTR);
  int*   H       = (int*)(ws + OFF_HIST);
  int*   total   = (int*)(ws + OFF_TOT);

  const int nchunk = (E + ECH - 1) / ECH;  // 391

  // ---- CSR build: counting sort (+ src-segment sort), zero global atomics
  histo_kernel<<<nchunk, 256, 0, stream>>>(dst, H, E, nchunk, W1, W2, w1t, w2t);
  bucket_scan_kernel<<<NB, 256, 0, stream>>>(H, total, nchunk);
  scatter_kernel<<<nchunk, 256, 0, stream>>>(src, dst, H, total, part, E, nchunk);
  bucket_csr_kernel<<<NB, 256, 0, stream>>>(part, total, row_ptr, dis, col, NN, E);

  // ---- layer 1 GEMM ----
  gemm_mfma_kernel<D_H1>
      <<<(NN + 63) / 64, 256, 0, stream>>>(x, w1t, dis, g1, NN);

  // ---- fused gather1 + ReLU + gemm2 ----
  gather1_gemm2_kernel<<<NN / 16, 256, 0, stream>>>(
      g1, col, row_ptr, dis, b1, w2t, g2, NN);

  // ---- fused gather2 + MFMA head + softmax ----
  gather2_final_kernel<<<(NN + 31) / 32, 256, 0, stream>>>(
      g2, col, row_ptr, dis, b2, Wf, bf, out, NN);
}

// Round 3
// 239.280 us; speedup vs baseline: 1.1045x; 1.0194x over previous
//
#include <hip/hip_runtime.h>
#include <math.h>

#define NN 100000
#define D_IN 128
#define D_H1 128
#define D_H2 64
#define D_O 10
#define NB 256          // node buckets for counting-sort CSR build
#define BDIV 391        // bucket(d) = d / 391  (255*391 = 99705 <= d < 100000 -> 255)
#define ECH 4096        // edges per chunk (scatter)
#define PCAP 7168       // fixed per-bucket capacity (mean 6250, sigma 79 -> +11.6s)
#define S_SEG 16        // src segments per adjacency list
#define SEGW 6250       // nodes per src segment

// ---- workspace layout (bytes) ----
static const size_t OFF_G1     = 0;                 // N*128 bf16 = 25.6 MB
static const size_t OFF_G2     = 25600000;          // N*64 bf16 = 12.8 MB
static const size_t OFF_W1T    = 40000000;          // 128*128 bf16 = 32 KB
static const size_t OFF_W2T    = 40100000;          // 64*128 bf16 = 16 KB
static const size_t OFF_PART   = 76800000;          // NB*PCAP u32 = 7.34 MB
static const size_t OFF_COL    = 90000000;          // NB*PCAP i32 = 7.34 MB
static const size_t OFF_DIS    = 98000000;          // N f32
static const size_t OFF_RP     = 98500000;          // N i32 (row start)
static const size_t OFF_RE     = 99000000;          // N i32 (row end)
static const size_t OFF_CUR    = 99500000;          // NB i32 (global bucket cursors)

typedef __attribute__((ext_vector_type(8))) short short8;
typedef __attribute__((ext_vector_type(4))) float floatx4;

// ---- bf16 helpers (RNE; values are finite) ----
__device__ inline unsigned int pack_bf2(float a, float b) {
  unsigned int ua = __float_as_uint(a);
  ua += 0x7fffu + ((ua >> 16) & 1u);
  unsigned int ub = __float_as_uint(b);
  ub += 0x7fffu + ((ub >> 16) & 1u);
  return (ua >> 16) | (ub & 0xffff0000u);
}
__device__ inline unsigned short bf16u(float a) {
  unsigned int ua = __float_as_uint(a);
  ua += 0x7fffu + ((ua >> 16) & 1u);
  return (unsigned short)(ua >> 16);
}
__device__ inline float bflo(unsigned int u) { return __uint_as_float(u << 16); }
__device__ inline float bfhi(unsigned int u) { return __uint_as_float(u & 0xffff0000u); }
__device__ inline short8 as_short8(uint4 u) {
  union { uint4 u4; short8 s8; } c; c.u4 = u; return c.s8;
}
__device__ inline void acc_u4(float* acc, uint4 u) {
  acc[0] += bflo(u.x); acc[1] += bfhi(u.x);
  acc[2] += bflo(u.y); acc[3] += bfhi(u.y);
  acc[4] += bflo(u.z); acc[5] += bfhi(u.z);
  acc[6] += bflo(u.w); acc[7] += bfhi(u.w);
}
__device__ inline void acc_u4s(float* acc, uint4 u, float sc) {
  acc[0] = fmaf(sc, bflo(u.x), acc[0]);
  acc[1] = fmaf(sc, bfhi(u.x), acc[1]);
  acc[2] = fmaf(sc, bflo(u.y), acc[2]);
  acc[3] = fmaf(sc, bfhi(u.y), acc[3]);
  acc[4] = fmaf(sc, bflo(u.z), acc[4]);
  acc[5] = fmaf(sc, bfhi(u.z), acc[5]);
  acc[6] = fmaf(sc, bflo(u.w), acc[6]);
  acc[7] = fmaf(sc, bfhi(u.w), acc[7]);
}

// ---- K1: fused histo+scan+scatter (fixed-cap bucket segments, run reservation
// via one global atomicAdd per (block,bucket)) + one-time weight pack role.
// part entry packed: (d_local << 17) | src.
__global__ __launch_bounds__(256) void scatter_pack_kernel(
    const int* __restrict__ src, const int* __restrict__ dst,
    int* __restrict__ cursor, unsigned int* __restrict__ part,
    int E, int nchunk,
    const float* __restrict__ W1, const float* __restrict__ W2,
    unsigned short* __restrict__ w1t, unsigned short* __restrict__ w2t) {
  const int tid = threadIdx.x;
  const int bid = blockIdx.x;
  if (bid >= nchunk) {   // weight-pack role (96 blocks)
    int pb = bid - nchunk;
    if (pb < 64) {       // W1^T: [128][128] bf16
      int o = pb * 256 + tid;
      int nn = o >> 7, k = o & 127;
      w1t[o] = bf16u(W1[(size_t)k * D_H1 + nn]);
    } else {             // W2^T: [64][128] bf16
      int o = (pb - 64) * 256 + tid;
      int nn = o >> 7, k = o & 127;
      w2t[o] = bf16u(W2[(size_t)k * D_H2 + nn]);
    }
    return;
  }
  __shared__ int dloc[ECH];   // cached dst values, 16 KB
  __shared__ int cnt[NB];
  __shared__ int rbase[NB];
  __shared__ int rnk[NB];
  cnt[tid] = 0;
  __syncthreads();
  const int e0 = bid * ECH;
#pragma unroll
  for (int i = 0; i < ECH / 256; ++i) {
    int e = e0 + i * 256 + tid;
    int d = (e < E) ? dst[e] : -1;
    dloc[i * 256 + tid] = d;
    if (d >= 0) atomicAdd(&cnt[d / BDIV], 1);
  }
  __syncthreads();
  rbase[tid] = atomicAdd(&cursor[tid], cnt[tid]);  // reserve run in bucket tid
  rnk[tid] = 0;
  __syncthreads();
#pragma unroll
  for (int i = 0; i < ECH / 256; ++i) {
    int e = e0 + i * 256 + tid;
    if (e < E) {
      int d = dloc[i * 256 + tid];
      int s = src[e];
      int b = d / BDIV;
      int r = rbase[b] + atomicAdd(&rnk[b], 1);  // LDS rank within run
      if (r < PCAP)
        part[(size_t)b * PCAP + r] =
            ((unsigned int)(d - b * BDIV) << 17) | (unsigned int)s;
    }
  }
}

// ---- K2: role-split kernel.
// Blocks [0,NB): per-bucket CSR finalize with src-segment sort -> row_ptr,
//   row_end, dis, col (fixed-cap layout, hence separate row_end).
// Blocks [NB, NB+1563): dense MFMA gemm1: g1 = bf16(x @ W1) (NOT dis-scaled;
//   dis is being produced concurrently by the csr blocks -- gather1 applies
//   dis[src] per gathered row instead).
// LDS union: csr needs 53.7 KB, gemm needs 34.8 KB -> 53.8 KB, 3 blocks/CU.
#define TOT (BDIV * S_SEG)   // 6256
__global__ __launch_bounds__(256) void csr_gemm_kernel(
    const unsigned int* __restrict__ part, const int* __restrict__ cursor,
    int* __restrict__ row_ptr, int* __restrict__ row_end,
    float* __restrict__ dis, int* __restrict__ col,
    const float* __restrict__ A_, const unsigned short* __restrict__ w1t,
    unsigned short* __restrict__ g1, int n) {
  __shared__ char smu[53760];
  const int tid = threadIdx.x;

  if (blockIdx.x < NB) {
    // ================= CSR role =================
    int* cnt2 = (int*)smu;                    // (TOT+1) ints = 25028 B
    int* col_s = (int*)(smu + 25056);         // PCAP ints = 28672 B
    int* wsum = (int*)(smu + 25056 + 28672);  // 4 ints
    const int b = blockIdx.x;
    const int lo = b * BDIV;
    const int nn = min(n - lo, BDIV);
    const int ecnt = min(cursor[b], PCAP);
    const int ebase = b * PCAP;
    for (int t = tid; t <= TOT; t += 256) cnt2[t] = 0;
    __syncthreads();
    // P1: per-(node,seg) count (LDS atomics)
    for (int i0 = 0; i0 < ecnt; i0 += 256) {
      int idx = i0 + tid;
      if (idx < ecnt) {
        unsigned int p = part[(size_t)ebase + idx];
        int s = (int)(p & 0x1FFFFu);
        atomicAdd(&cnt2[(int)(p >> 17) * S_SEG + s / SEGW], 1);
      }
    }
    __syncthreads();
    // P2: in-place exclusive scan of cnt2[0..TOT) via wave-shuffle scan
    {
      const int lane = tid & 63;
      const int wv = tid >> 6;
      int carry = 0;
      for (int t0 = 0; t0 < TOT; t0 += 1024) {
        int i0 = t0 + tid * 4;
        int v0 = (i0 + 0 < TOT) ? cnt2[i0 + 0] : 0;
        int v1 = (i0 + 1 < TOT) ? cnt2[i0 + 1] : 0;
        int v2 = (i0 + 2 < TOT) ? cnt2[i0 + 2] : 0;
        int v3 = (i0 + 3 < TOT) ? cnt2[i0 + 3] : 0;
        int ts = v0 + v1 + v2 + v3;
        int incl = ts;
#pragma unroll
        for (int off = 1; off < 64; off <<= 1) {
          int o = __shfl_up(incl, off);
          if (lane >= off) incl += o;
        }
        if (lane == 63) wsum[wv] = incl;
        __syncthreads();
        int wpre = 0;
#pragma unroll
        for (int w = 0; w < 4; ++w)
          if (w < wv) wpre += wsum[w];
        int btot = wsum[0] + wsum[1] + wsum[2] + wsum[3];
        int e = carry + wpre + (incl - ts);
        __syncthreads();  // wsum reads done before next-tile writes
        if (i0 + 0 < TOT) cnt2[i0 + 0] = e;
        if (i0 + 1 < TOT) cnt2[i0 + 1] = e + v0;
        if (i0 + 2 < TOT) cnt2[i0 + 2] = e + v0 + v1;
        if (i0 + 3 < TOT) cnt2[i0 + 3] = e + v0 + v1 + v2;
        carry += btot;
      }
      if (tid == 0) cnt2[TOT] = carry;
    }
    __syncthreads();
    // row_ptr/row_end/dis from pristine offsets
    for (int t = tid; t < nn; t += 256) {
      int b0 = cnt2[t * S_SEG];
      int b1 = cnt2[(t + 1) * S_SEG];
      row_ptr[lo + t] = ebase + b0;
      row_end[lo + t] = ebase + b1;
      dis[lo + t] = rsqrtf((float)(b1 - b0) + 1.0f);
    }
    __syncthreads();  // offset reads done before P3 mutates cnt2
    // P3: bin srcs into LDS col by (node,seg)
    for (int i0 = 0; i0 < ecnt; i0 += 256) {
      int idx = i0 + tid;
      if (idx < ecnt) {
        unsigned int p = part[(size_t)ebase + idx];
        int s = (int)(p & 0x1FFFFu);
        int r = atomicAdd(&cnt2[(int)(p >> 17) * S_SEG + s / SEGW], 1);
        if (r < PCAP) col_s[r] = s;
      }
    }
    __syncthreads();
    // P4: coalesced col writeback
    for (int idx = tid; idx < ecnt; idx += 256) col[(size_t)ebase + idx] = col_s[idx];
  } else {
    // ================= GEMM role: g1 = bf16(x @ W1), K=128, NOUT=128 =========
    constexpr int K = 128;
    constexpr int NOUT = D_H1;
    constexpr int NT = NOUT / 16;
    constexpr int LDW = K + 8;  // 272B row stride: b128 conflict-free
    unsigned short* wt = (unsigned short*)smu;   // NOUT*LDW shorts = 34.8 KB
    unsigned short* buf = wt;                    // reused after barrier
    const int gb = blockIdx.x - NB;

    // stage W^T bf16 -> LDS, coalesced
    {
      const uint4* wsrc = (const uint4*)w1t;  // NOUT*16 uint4
#pragma unroll
      for (int j = 0; j < NOUT * K / (8 * 256); ++j) {
        int o = tid + j * 256;
        int row = o >> 4;
        int k8 = (o & 15) * 8;
        *(uint4*)(wt + row * LDW + k8) = wsrc[o];
      }
    }

    const int wave = tid >> 6;
    const int lane = tid & 63;
    const int quad = lane >> 4;
    const int cg = lane & 15;
    const int row0w = gb * 64 + wave * 16;

    short8 afr[4];
    {
      int row = row0w + cg;
      if (row > n - 1) row = n - 1;  // clamp: garbage rows never stored
#pragma unroll
      for (int kb = 0; kb < 4; ++kb) {
        const float* p = A_ + (size_t)row * K + kb * 32 + quad * 8;
        float4 v0 = *(const float4*)(p);
        float4 v1 = *(const float4*)(p + 4);
        uint4 u;
        u.x = pack_bf2(v0.x, v0.y); u.y = pack_bf2(v0.z, v0.w);
        u.z = pack_bf2(v1.x, v1.y); u.w = pack_bf2(v1.z, v1.w);
        afr[kb] = as_short8(u);
      }
    }
    __syncthreads();

    floatx4 acc[NT];
#pragma unroll
    for (int t = 0; t < NT; ++t) acc[t] = (floatx4){0.f, 0.f, 0.f, 0.f};
#pragma unroll
    for (int t = 0; t < NT; ++t) {
      const unsigned short* wrow = wt + (t * 16 + cg) * LDW;
#pragma unroll
      for (int kb = 0; kb < 4; ++kb) {
        short8 bfr = *(const short8*)(wrow + kb * 32 + quad * 8);
        acc[t] = __builtin_amdgcn_mfma_f32_16x16x32_bf16(afr[kb], bfr, acc[t], 0, 0, 0);
      }
    }
    __syncthreads();  // all wt reads done before reuse as buf

    unsigned short* mybuf = buf + wave * 16 * LDW;
#pragma unroll
    for (int t = 0; t < NT; ++t)
#pragma unroll
      for (int r = 0; r < 4; ++r)
        mybuf[(quad * 4 + r) * LDW + t * 16 + cg] = bf16u(acc[t][r]);
    __syncthreads();

    constexpr int CHUNKS = NOUT / 8;
    constexpr int RPI = 64 / CHUNKS;
    int cid = lane % CHUNKS;
    int rs = lane / CHUNKS;
#pragma unroll
    for (int i = 0; i < 16 / RPI; ++i) {
      int r = rs + i * RPI;
      int grow = row0w + r;
      if (grow < n) {
        uint4 u = *(const uint4*)(mybuf + r * LDW + cid * 8);
        *(uint4*)(g1 + (size_t)grow * NOUT + cid * 8) = u;
      }
    }
  }
}

// ---- K3: fused layer-1 gather (dis[src]-weighted) + ReLU + gemm2 -> g2.
// Block = 16 nodes; grid = NN/16 exactly.
__global__ __launch_bounds__(256) void gather1_gemm2_kernel(
    const unsigned short* __restrict__ g, const int* __restrict__ col,
    const int* __restrict__ row_ptr, const int* __restrict__ row_end,
    const float* __restrict__ dis, const float* __restrict__ b1,
    const unsigned short* __restrict__ w2t,
    unsigned short* __restrict__ g2, int n) {
  constexpr int K = D_H1;        // 128
  constexpr int LDW = K + 8;     // 136
  constexpr int LDO = 80;        // 160B row stride
  __shared__ unsigned short wt[D_H2 * LDW];   // W2^T bf16, 17.4 KB
  __shared__ unsigned short hl[16 * LDW];     // h tile bf16, 4.4 KB
  __shared__ unsigned short obuf[16 * LDO];   // out tile, 2.56 KB
  const int tid = threadIdx.x;
  const int row0 = blockIdx.x * 16;

  // stage W2^T bf16 -> LDS, coalesced (1024 uint4)
  {
    const uint4* wsrc = (const uint4*)w2t;
#pragma unroll
    for (int j = 0; j < 4; ++j) {
      int o = tid + j * 256;
      int row = o >> 4;
      int k8 = (o & 15) * 8;
      *(uint4*)(wt + row * LDW + k8) = wsrc[o];
    }
  }

  // ---- gather phase: 16 nodes x 16 lanes x 8 feats ----
  {
    const int v = row0 + (tid >> 4);
    const int c = (tid & 15) * 8;
    const int start = row_ptr[v];
    const int end = row_end[v];
    const float dv = dis[v];
    float acc[8];
#pragma unroll
    for (int q = 0; q < 8; ++q) acc[q] = 0.f;
    acc_u4s(acc, *(const uint4*)(g + (size_t)v * K + c), dv);  // self-loop
    int e = start;
    for (; e + 4 <= end; e += 4) {
      int s0 = col[e + 0], s1 = col[e + 1], s2 = col[e + 2], s3 = col[e + 3];
      float q0 = dis[s0], q1 = dis[s1], q2 = dis[s2], q3 = dis[s3];
      uint4 u0 = *(const uint4*)(g + (size_t)s0 * K + c);
      uint4 u1 = *(const uint4*)(g + (size_t)s1 * K + c);
      uint4 u2 = *(const uint4*)(g + (size_t)s2 * K + c);
      uint4 u3 = *(const uint4*)(g + (size_t)s3 * K + c);
      acc_u4s(acc, u0, q0); acc_u4s(acc, u1, q1);
      acc_u4s(acc, u2, q2); acc_u4s(acc, u3, q3);
    }
    for (; e < end; ++e) {
      int s = col[e];
      acc_u4s(acc, *(const uint4*)(g + (size_t)s * K + c), dis[s]);
    }
    float4 bv0 = *(const float4*)(b1 + c);
    float4 bv1 = *(const float4*)(b1 + c + 4);
    float r0 = fmaxf(dv * acc[0] + bv0.x, 0.f);
    float r1 = fmaxf(dv * acc[1] + bv0.y, 0.f);
    float r2 = fmaxf(dv * acc[2] + bv0.z, 0.f);
    float r3 = fmaxf(dv * acc[3] + bv0.w, 0.f);
    float r4 = fmaxf(dv * acc[4] + bv1.x, 0.f);
    float r5 = fmaxf(dv * acc[5] + bv1.y, 0.f);
    float r6 = fmaxf(dv * acc[6] + bv1.z, 0.f);
    float r7 = fmaxf(dv * acc[7] + bv1.w, 0.f);
    uint4 o;
    o.x = pack_bf2(r0, r1);
    o.y = pack_bf2(r2, r3);
    o.z = pack_bf2(r4, r5);
    o.w = pack_bf2(r6, r7);
    *(uint4*)(hl + (tid >> 4) * LDW + c) = o;
  }
  __syncthreads();

  // ---- MFMA phase: wave t computes cols [16t, 16t+16) of the 16x64 tile ----
  {
    const int wave = tid >> 6;
    const int lane = tid & 63;
    const int quad = lane >> 4;
    const int cg = lane & 15;
    floatx4 acc = (floatx4){0.f, 0.f, 0.f, 0.f};
    const unsigned short* wrow = wt + (wave * 16 + cg) * LDW;
    const unsigned short* arow = hl + cg * LDW;
#pragma unroll
    for (int kb = 0; kb < 4; ++kb) {
      short8 afr = *(const short8*)(arow + kb * 32 + quad * 8);
      short8 bfr = *(const short8*)(wrow + kb * 32 + quad * 8);
      acc = __builtin_amdgcn_mfma_f32_16x16x32_bf16(afr, bfr, acc, 0, 0, 0);
    }
    float4 dv4 = *(const float4*)(dis + row0 + quad * 4);
    float dvs[4] = {dv4.x, dv4.y, dv4.z, dv4.w};
#pragma unroll
    for (int r = 0; r < 4; ++r)
      obuf[(quad * 4 + r) * LDO + wave * 16 + cg] = bf16u(acc[r] * dvs[r]);
  }
  __syncthreads();

  if (tid < 128) {
    int r = tid >> 3;
    int cid = tid & 7;
    uint4 u = *(const uint4*)(obuf + r * LDO + cid * 8);
    *(uint4*)(g2 + (size_t)(row0 + r) * D_H2 + cid * 8) = u;
  }
}

// ---- K4: fused layer-2 gather + ReLU + MFMA head + softmax. g bf16 (F=64).
__global__ __launch_bounds__(256) void gather2_final_kernel(
    const unsigned short* __restrict__ g, const int* __restrict__ col,
    const int* __restrict__ row_ptr, const int* __restrict__ row_end,
    const float* __restrict__ dis, const float* __restrict__ b2,
    const float* __restrict__ Wf, const float* __restrict__ bf,
    float* __restrict__ out, int n) {
  constexpr int LDH = 72;  // bf16 stride: 144B, 16B-aligned
  __shared__ unsigned short ha[32 * LDH];   // h2 tile bf16
  __shared__ unsigned short wtf[16 * LDH];  // Wf^T bf16, padded N=16
  __shared__ float bfs[D_O];
  __shared__ float ls[32][12];
  const int tid = threadIdx.x;
  if (tid < 128) {
    int nn = tid >> 3;
    int k = (tid & 7) * 8;
    uint4 u;
    if (nn < D_O) {
      u.x = pack_bf2(Wf[(size_t)(k + 0) * D_O + nn], Wf[(size_t)(k + 1) * D_O + nn]);
      u.y = pack_bf2(Wf[(size_t)(k + 2) * D_O + nn], Wf[(size_t)(k + 3) * D_O + nn]);
      u.z = pack_bf2(Wf[(size_t)(k + 4) * D_O + nn], Wf[(size_t)(k + 5) * D_O + nn]);
      u.w = pack_bf2(Wf[(size_t)(k + 6) * D_O + nn], Wf[(size_t)(k + 7) * D_O + nn]);
    } else {
      u = make_uint4(0u, 0u, 0u, 0u);
    }
    *(uint4*)(wtf + nn * LDH + k) = u;
  }
  if (tid < D_O) bfs[tid] = bf[tid];

  const int gid = blockIdx.x * 256 + tid;
  const int v = gid >> 3;
  const int nl = tid >> 3;
  const int c = (tid & 7) * 8;
  if (v < n) {
    int start = row_ptr[v];
    int end = row_end[v];
    float acc[8];
#pragma unroll
    for (int q = 0; q < 8; ++q) acc[q] = 0.f;
    acc_u4(acc, *(const uint4*)(g + (size_t)v * D_H2 + c));  // self-loop
    int e = start;
    for (; e + 4 <= end; e += 4) {
      int s0 = col[e + 0], s1 = col[e + 1], s2 = col[e + 2], s3 = col[e + 3];
      uint4 u0 = *(const uint4*)(g + (size_t)s0 * D_H2 + c);
      uint4 u1 = *(const uint4*)(g + (size_t)s1 * D_H2 + c);
      uint4 u2 = *(const uint4*)(g + (size_t)s2 * D_H2 + c);
      uint4 u3 = *(const uint4*)(g + (size_t)s3 * D_H2 + c);
      acc_u4(acc, u0); acc_u4(acc, u1); acc_u4(acc, u2); acc_u4(acc, u3);
    }
    for (; e < end; ++e) {
      uint4 u = *(const uint4*)(g + (size_t)col[e] * D_H2 + c);
      acc_u4(acc, u);
    }
    float dv = dis[v];
    float4 bv0 = *(const float4*)(b2 + c);
    float4 bv1 = *(const float4*)(b2 + c + 4);
    float r0 = fmaxf(dv * acc[0] + bv0.x, 0.f);
    float r1 = fmaxf(dv * acc[1] + bv0.y, 0.f);
    float r2 = fmaxf(dv * acc[2] + bv0.z, 0.f);
    float r3 = fmaxf(dv * acc[3] + bv0.w, 0.f);
    float r4 = fmaxf(dv * acc[4] + bv1.x, 0.f);
    float r5 = fmaxf(dv * acc[5] + bv1.y, 0.f);
    float r6 = fmaxf(dv * acc[6] + bv1.z, 0.f);
    float r7 = fmaxf(dv * acc[7] + bv1.w, 0.f);
    uint4 o;
    o.x = pack_bf2(r0, r1);
    o.y = pack_bf2(r2, r3);
    o.z = pack_bf2(r4, r5);
    o.w = pack_bf2(r6, r7);
    *(uint4*)(ha + nl * LDH + c) = o;
  }
  __syncthreads();
  // ---- MFMA head: waves 0/1 -> 16 nodes x 16 classes each (K=64) ----
  {
    const int wave = tid >> 6;
    if (wave < 2) {
      const int lane = tid & 63;
      const int quad = lane >> 4;
      const int cg = lane & 15;
      floatx4 acc = (floatx4){0.f, 0.f, 0.f, 0.f};
      const unsigned short* arow = ha + (wave * 16 + cg) * LDH;
      const unsigned short* wrow = wtf + cg * LDH;
#pragma unroll
      for (int kb = 0; kb < 2; ++kb) {
        short8 afr = *(const short8*)(arow + kb * 32 + quad * 8);
        short8 bfr = *(const short8*)(wrow + kb * 32 + quad * 8);
        acc = __builtin_amdgcn_mfma_f32_16x16x32_bf16(afr, bfr, acc, 0, 0, 0);
      }
      if (cg < D_O) {
        float bb = bfs[cg];
#pragma unroll
        for (int r = 0; r < 4; ++r)
          ls[wave * 16 + quad * 4 + r][cg] = acc[r] + bb;
      }
    }
  }
  __syncthreads();
  if (tid < 32) {
    int v2 = blockIdx.x * 32 + tid;
    if (v2 < n) {
      float m = ls[tid][0];
#pragma unroll
      for (int j = 1; j < D_O; ++j) m = fmaxf(m, ls[tid][j]);
      float s = 0.f;
      float ex[D_O];
#pragma unroll
      for (int j = 0; j < D_O; ++j) { ex[j] = expf(ls[tid][j] - m); s += ex[j]; }
      float inv = 1.0f / s;
#pragma unroll
      for (int j = 0; j < D_O; ++j) ls[tid][j] = ex[j] * inv;
    }
  }
  __syncthreads();
  for (int idx = tid; idx < 32 * D_O; idx += 256) {
    int gidx = blockIdx.x * 32 * D_O + idx;
    if (gidx < n * D_O) out[gidx] = ls[idx / D_O][idx % D_O];
  }
}

extern "C" void kernel_launch(void* const* d_in, const int* in_sizes, int n_in,
                              void* d_out, int out_size, void* d_ws, size_t ws_size,
                              hipStream_t stream) {
  const float* x  = (const float*)d_in[0];
  const int*   ei = (const int*)d_in[1];
  const float* W1 = (const float*)d_in[2];
  const float* b1 = (const float*)d_in[3];
  const float* W2 = (const float*)d_in[4];
  const float* b2 = (const float*)d_in[5];
  const float* Wf = (const float*)d_in[6];
  const float* bf = (const float*)d_in[7];
  float* out = (float*)d_out;

  const int E = in_sizes[1] / 2;
  const int* src = ei;
  const int* dst = ei + E;

  char* ws = (char*)d_ws;
  unsigned short* g1 = (unsigned short*)(ws + OFF_G1);
  unsigned short* g2 = (unsigned short*)(ws + OFF_G2);
  unsigned short* w1t = (unsigned short*)(ws + OFF_W1T);
  unsigned short* w2t = (unsigned short*)(ws + OFF_W2T);
  unsigned int* part = (unsigned int*)(ws + OFF_PART);
  int*   col     = (int*)(ws + OFF_COL);
  float* dis     = (float*)(ws + OFF_DIS);
  int*   row_ptr = (int*)(ws + OFF_RP);
  int*   row_end = (int*)(ws + OFF_RE);
  int*   cursor  = (int*)(ws + OFF_CUR);

  const int nchunk = (E + ECH - 1) / ECH;  // 391

  hipMemsetAsync(cursor, 0, NB * sizeof(int), stream);

  // K1: fused histo+scan+scatter + weight pack
  scatter_pack_kernel<<<nchunk + 96, 256, 0, stream>>>(
      src, dst, cursor, part, E, nchunk, W1, W2, w1t, w2t);

  // K2: bucket CSR finalize (blocks 0..255) || dense gemm1 (blocks 256..)
  csr_gemm_kernel<<<NB + (NN + 63) / 64, 256, 0, stream>>>(
      part, cursor, row_ptr, row_end, dis, col, x, w1t, g1, NN);

  // K3: fused gather1 + ReLU + gemm2
  gather1_gemm2_kernel<<<NN / 16, 256, 0, stream>>>(
      g1, col, row_ptr, row_end, dis, b1, w2t, g2, NN);

  // K4: fused gather2 + MFMA head + softmax
  gather2_final_kernel<<<(NN + 31) / 32, 256, 0, stream>>>(
      g2, col, row_ptr, row_end, dis, b2, Wf, bf, out, NN);
}